// Round 10
// baseline (537.082 us; speedup 1.0000x reference)
//
#include <hip/hip_runtime.h>

// AnchorStore: KL-argmin 1-NN.
//   score[b,k] = sum_d A[k,d]*log A[k,d]  -  sum_d A[k,d]*log Q[b,d]
//   out[b] = label[argmin_k score[b,k]],  K=2048, D=50257, B=256.
//
// Round-9: barrier-free register-tile GEMM. Cross-round invariant r4/r7/r8:
// LDS-staged barrier-stepped loops cost ~4.4-5.4us/step (10K+ cycles of
// exposed latency; all resident waves stall at the same barrier). Fix: each
// wave independently computes k32 x b256 x D-subrange in registers (128 VGPR
// acc), Q read directly from a chunked bf16 log(Q) buffer lq[d/32][b][32]
// (1KB fully-coalesced wave-loads, z-slice L2-resident per XCD pair), A read
// once from HBM via unaligned float4 covers. No inner-loop barriers; 8 dsub
// waves per block tree-reduce their accs in LDS once at the end.
// Two-phase D-split keeps lq + fp32 partials inside the proven 28MB ws window.

constexpr int K    = 2048;
constexpr int D    = 50257;
constexpr int B    = 256;
constexpr int DSPL = 25344;          // phase-0 length (mult of 32)
constexpr int NC   = 8;
constexpr float MARGIN = 4.0f;

typedef __attribute__((ext_vector_type(8))) short bf16x8;
typedef __attribute__((ext_vector_type(4))) float f32x4;
typedef __attribute__((ext_vector_type(8))) unsigned short u16x8;

__device__ inline unsigned short f2bf_rne(float f) {
    union { float f; unsigned u; } v; v.f = f;
    unsigned r = v.u + 0x7FFFu + ((v.u >> 16) & 1u);
    return (unsigned short)(r >> 16);
}

// ---- lq[ch][b][32] = bf16(log(Q[b][aoff + ch*32 + c])), zero-padded past DL ----
__global__ __launch_bounds__(256)
void lq_kernel(const float* __restrict__ q, unsigned short* __restrict__ lq,
               int aoff, int DL, int nch)
{
    const int stride = gridDim.x * blockDim.x;
    const int total  = nch * B * 4;                  // 4 subs of 8 elems
    for (int c = blockIdx.x * blockDim.x + threadIdx.x; c < total; c += stride) {
        const int sub = c & 3;
        const int b   = (c >> 2) & 255;
        const int ch  = c >> 10;
        const int d0  = ch * 32 + sub * 8;
        u16x8 w;
#pragma unroll
        for (int j = 0; j < 8; ++j) {
            const int d = d0 + j;
            const float v = (d < DL) ? q[(size_t)b * D + aoff + d] : 1.f; // log(1)=0
            w[j] = f2bf_rne(__logf(v));
        }
        *reinterpret_cast<u16x8*>(&lq[((size_t)ch * B + b) * 32 + sub * 8]) = w;
    }
}

// ---- GEMM: part[z][B][K], selfp[zoff+z][K]; 8 waves = 8 D-subranges ----
__global__ __launch_bounds__(512)
void gemm_kernel(const float* __restrict__ anchor,
                 const unsigned short* __restrict__ lq,
                 float* __restrict__ part,     // [pch][B][K]
                 float* __restrict__ selfp,    // [2*pch][K]
                 int dc, int DL, int DCAP, int aoff, int zoff)
{
    // swizzle: XCD x hosts g in [x*nb8, (x+1)*nb8) -> one z per XCD pair (pch=4)
    const int nb8 = gridDim.x >> 3;
    const int g   = (blockIdx.x & 7) * nb8 + (blockIdx.x >> 3);
    const int z   = g >> 6;                       // 64 k-tiles per z
    const int kt  = g & 63;
    const int k0  = kt * 32;

    const int t    = threadIdx.x;
    const int wid  = t >> 6;                      // 0..7 = D-subrange
    const int lane = t & 63;
    const int lr   = lane & 15;                   // A-row / Q-b within tile
    const int lg   = lane >> 4;                   // 0..3 d-group

    // wave's D-subrange within z
    const int zd0 = z * dc;
    const int zd1 = min(zd0 + dc, DCAP);
    const int wd  = ((dc / 8) + 31) & ~31;
    const int d0  = zd0 + wid * wd;
    const int d1  = min(d0 + wd, zd1);

    const size_t KDm4 = (size_t)K * D - 4;

    f32x4 acc0[16], acc1[16];
#pragma unroll
    for (int j = 0; j < 16; ++j)
#pragma unroll
        for (int i = 0; i < 4; ++i) { acc0[j][i] = 0.f; acc1[j][i] = 0.f; }

    float sacc0 = 0.f, sacc1 = 0.f;

    if (d0 < d1) {
        const int ar0 = k0 + lr;
        const int ar1 = ar0 + 16;
        const size_t gA0 = (size_t)ar0 * D + aoff + d0 + lg * 8;
        const size_t gA1 = (size_t)ar1 * D + aoff + d0 + lg * 8;
        const int ph0 = (int)(gA0 & 3);
        const int ph1 = (int)(gA1 & 3);
        size_t iA0 = gA0 - ph0;
        size_t iA1 = gA1 - ph1;

        // lq per-lane base (ushort units): chunk*8192 + b-row*32 + lg*8
        const unsigned short* qp =
            lq + ((size_t)(d0 >> 5) * (B * 32) + (size_t)lr * 32 + lg * 8);

        auto ld4 = [&](size_t fi) -> float4 {
            if (fi > KDm4) fi = KDm4;             // clamped slots are masked below
            return *reinterpret_cast<const float4*>(anchor + fi);
        };

        for (int dd = d0; dd < d1; dd += 32) {
            const int dbase = dd + lg * 8;        // phase-local col of elem 0
            // ---- A row 0: cover, select, mask, self, bf16 ----
            bf16x8 af0, af1;
            {
                const float4 v0 = ld4(iA0), v1 = ld4(iA0 + 4), v2 = ld4(iA0 + 8);
                float wf[12] = {v0.x, v0.y, v0.z, v0.w, v1.x, v1.y, v1.z, v1.w,
                                v2.x, v2.y, v2.z, v2.w};
                float s9[9];
#pragma unroll
                for (int j = 0; j < 9; ++j) s9[j] = (ph0 & 2) ? wf[j + 2] : wf[j];
#pragma unroll
                for (int j = 0; j < 8; ++j) {
                    float a = (ph0 & 1) ? s9[j + 1] : s9[j];
                    a = (dbase + j < DL) ? a : 0.f;
                    if (a > 0.f) sacc0 = fmaf(a, __logf(a), sacc0);
                    af0[j] = (short)f2bf_rne(a);
                }
                iA0 += 32;
            }
            {
                const float4 v0 = ld4(iA1), v1 = ld4(iA1 + 4), v2 = ld4(iA1 + 8);
                float wf[12] = {v0.x, v0.y, v0.z, v0.w, v1.x, v1.y, v1.z, v1.w,
                                v2.x, v2.y, v2.z, v2.w};
                float s9[9];
#pragma unroll
                for (int j = 0; j < 9; ++j) s9[j] = (ph1 & 2) ? wf[j + 2] : wf[j];
#pragma unroll
                for (int j = 0; j < 8; ++j) {
                    float a = (ph1 & 1) ? s9[j + 1] : s9[j];
                    a = (dbase + j < DL) ? a : 0.f;
                    if (a > 0.f) sacc1 = fmaf(a, __logf(a), sacc1);
                    af1[j] = (short)f2bf_rne(a);
                }
                iA1 += 32;
            }
            // ---- Q frags + MFMA, two half-batches of 8 b-tiles ----
            {
                bf16x8 qf[8];
#pragma unroll
                for (int j = 0; j < 8; ++j)
                    qf[j] = *reinterpret_cast<const bf16x8*>(qp + j * 512);
#pragma unroll
                for (int j = 0; j < 8; ++j) {
                    acc0[j] = __builtin_amdgcn_mfma_f32_16x16x32_bf16(af0, qf[j], acc0[j], 0, 0, 0);
                    acc1[j] = __builtin_amdgcn_mfma_f32_16x16x32_bf16(af1, qf[j], acc1[j], 0, 0, 0);
                }
#pragma unroll
                for (int j = 0; j < 8; ++j)
                    qf[j] = *reinterpret_cast<const bf16x8*>(qp + (8 + j) * 512);
#pragma unroll
                for (int j = 0; j < 8; ++j) {
                    acc0[8 + j] = __builtin_amdgcn_mfma_f32_16x16x32_bf16(af0, qf[j], acc0[8 + j], 0, 0, 0);
                    acc1[8 + j] = __builtin_amdgcn_mfma_f32_16x16x32_bf16(af1, qf[j], acc1[8 + j], 0, 0, 0);
                }
            }
            qp += (size_t)B * 32;                 // next 32-chunk
        }
    }

    // ---- in-wave self reduce across lg groups -> lanes 0..15 hold row sums ----
    sacc0 += __shfl_xor(sacc0, 16); sacc0 += __shfl_xor(sacc0, 32);
    sacc1 += __shfl_xor(sacc1, 16); sacc1 += __shfl_xor(sacc1, 32);

    // ---- block-level reduction: 4 LDS regions [256][36] f32 + self scratch ----
    __shared__ __align__(16) float red[4][256 * 36];    // 147,456 B
    __shared__ float sred[8][32];

    if (lane < 16) { sred[wid][lr] = sacc0; sred[wid][16 + lr] = sacc1; }

    const int rbase = wid & 3;
    if (wid < 4) {
#pragma unroll
        for (int bt = 0; bt < 16; ++bt) {
            float* p0 = &red[rbase][(bt * 16 + lr) * 36 + lg * 4];
            *reinterpret_cast<f32x4*>(p0)      = acc0[bt];
            *reinterpret_cast<f32x4*>(p0 + 16) = acc1[bt];
        }
    }
    __syncthreads();
    if (wid >= 4) {
#pragma unroll
        for (int bt = 0; bt < 16; ++bt) {
            float* p0 = &red[rbase][(bt * 16 + lr) * 36 + lg * 4];
            f32x4 v0 = *reinterpret_cast<f32x4*>(p0);
            f32x4 v1 = *reinterpret_cast<f32x4*>(p0 + 16);
#pragma unroll
            for (int i = 0; i < 4; ++i) { v0[i] += acc0[bt][i]; v1[i] += acc1[bt][i]; }
            *reinterpret_cast<f32x4*>(p0)      = v0;
            *reinterpret_cast<f32x4*>(p0 + 16) = v1;
        }
    }
    __syncthreads();
    for (int i = t; i < 256 * 36; i += 512) {
        red[0][i] += red[2][i];
        red[1][i] += red[3][i];
    }
    __syncthreads();
    for (int i = t; i < 256 * 36; i += 512) red[0][i] += red[1][i];
    if (t < 32) {                               // self over 8 waves (sred ready)
        float s = 0.f;
#pragma unroll
        for (int w8 = 0; w8 < 8; ++w8) s += sred[w8][t];
        selfp[(size_t)(zoff + z) * K + k0 + t] = s;
    }
    __syncthreads();
    for (int i = t; i < 2048; i += 512) {       // 256b x 8 f32x4 = k32
        const int b  = i >> 3;
        const int kq = i & 7;
        const f32x4 v = *reinterpret_cast<f32x4*>(&red[0][b * 36 + kq * 4]);
        *reinterpret_cast<f32x4*>(&part[((size_t)z * B + b) * K + k0 + kq * 4]) = v;
    }
}

// ---- crossA[i] = sum_z part[z][i] (phase-0 fold) ----
__global__ __launch_bounds__(256)
void reduce_kernel(const float* __restrict__ part, float* __restrict__ crossA, int pch)
{
    const int i = blockIdx.x * 256 + threadIdx.x;
    const f32x4* p4 = reinterpret_cast<const f32x4*>(part);
    f32x4 s = p4[i];
    for (int z = 1; z < pch; ++z) {
        const f32x4 v = p4[(size_t)z * (B * K / 4) + i];
#pragma unroll
        for (int j = 0; j < 4; ++j) s[j] += v[j];
    }
    reinterpret_cast<f32x4*>(crossA)[i] = s;
}

// ---- reduce self partials over 2*pch rows ----
__global__ __launch_bounds__(256)
void selfsum_kernel(const float* __restrict__ selfp, float* __restrict__ selftot, int rows)
{
    const int k = blockIdx.x * 256 + threadIdx.x;
    float s = 0.f;
    for (int z = 0; z < rows; ++z) s += selfp[(size_t)z * K + k];
    selftot[k] = s;
}

// ---- per-query top-NC + rescore-need gap flag ----
__global__ __launch_bounds__(256)
void topk_kernel(const float* __restrict__ crossA, const float* __restrict__ part,
                 const float* __restrict__ selftot,
                 int* __restrict__ cand, int* __restrict__ need, int pch)
{
    const int b = blockIdx.x, t = threadIdx.x;
    float v[8];
#pragma unroll
    for (int i = 0; i < 8; ++i) {
        const int k = i * 256 + t;
        float cv = crossA[(size_t)b * K + k];
        for (int z = 0; z < pch; ++z) cv += part[((size_t)z * B + b) * K + k];
        v[i] = selftot[k] - cv;
    }
    __shared__ float sv[256];
    __shared__ int   si[256];
    __shared__ float topv[2];
    for (int r = 0; r < NC; ++r) {
        float bv = 3.4e38f; int bk = K;
#pragma unroll
        for (int i = 0; i < 8; ++i) {
            const int k = i * 256 + t;
            if (v[i] < bv) { bv = v[i]; bk = k; }
        }
        sv[t] = bv; si[t] = bk;
        __syncthreads();
        for (int off = 128; off > 0; off >>= 1) {
            if (t < off) {
                if (sv[t + off] < sv[t] || (sv[t + off] == sv[t] && si[t + off] < si[t])) {
                    sv[t] = sv[t + off]; si[t] = si[t + off];
                }
            }
            __syncthreads();
        }
        const int kwin = si[0];
        if ((kwin & 255) == t) v[kwin >> 8] = 3.4e38f;
        if (t == 0) {
            cand[b * NC + r] = kwin;
            if (r < 2) topv[r] = sv[0];
        }
        __syncthreads();
    }
    if (t == 0) need[b] = (topv[1] - topv[0] < MARGIN) ? 1 : 0;
}

// ---- exact fp64 rescore of flagged queries (D split in halves) ----
__global__ __launch_bounds__(512)
void rescore_kernel(const float* __restrict__ query, const float* __restrict__ anchor,
                    const int* __restrict__ cand, const int* __restrict__ need,
                    double* __restrict__ pp)
{
    const int b = blockIdx.x, h = blockIdx.y, t = threadIdx.x;
    if (!need[b]) return;   // uniform exit before any barrier
    const int dlo = h * 25129;
    const int dhi = min(D, dlo + 25129);
    int ks[NC];
#pragma unroll
    for (int c = 0; c < NC; ++c) ks[c] = cand[b * NC + c];
    const float* qrow = query + (size_t)b * D;

    double a8[NC];
#pragma unroll
    for (int c = 0; c < NC; ++c) a8[c] = 0.0;

    for (int d = dlo + t; d < dhi; d += 512) {
        const double lqv = (double)logf(qrow[d]);
#pragma unroll
        for (int c = 0; c < NC; ++c)
            a8[c] = fma((double)anchor[(size_t)ks[c] * D + d], lqv, a8[c]);
    }

    __shared__ double red[512];
    for (int c = 0; c < NC; ++c) {
        red[t] = a8[c];
        __syncthreads();
        for (int off = 256; off > 0; off >>= 1) {
            if (t < off) red[t] += red[t + off];
            __syncthreads();
        }
        if (t == 0) pp[((size_t)b * 2 + h) * NC + c] = red[0];
        __syncthreads();
    }
}

// ---- final decision + label gather ----
__global__ __launch_bounds__(256)
void final_kernel(const double* __restrict__ pp, const float* __restrict__ selftot,
                  const int* __restrict__ cand, const int* __restrict__ need,
                  const int* __restrict__ label, int* __restrict__ out)
{
    const int b = threadIdx.x;
    if (!need[b]) { out[b] = label[cand[b * NC]]; return; }
    float best = 3.4e38f; int bk = K;
#pragma unroll
    for (int c = 0; c < NC; ++c) {
        const int k = cand[b * NC + c];
        const double cv = pp[((size_t)b * 2 + 0) * NC + c] + pp[((size_t)b * 2 + 1) * NC + c];
        const float sc = selftot[k] - (float)cv;
        if (sc < best || (sc == best && k < bk)) { best = sc; bk = k; }
    }
    out[b] = label[bk];
}

extern "C" void kernel_launch(void* const* d_in, const int* in_sizes, int n_in,
                              void* d_out, int out_size, void* d_ws, size_t ws_size,
                              hipStream_t stream)
{
    const float* query  = (const float*)d_in[0];   // [B*D]
    const float* anchor = (const float*)d_in[1];   // [K*D]
    const int*   label  = (const int*)d_in[2];     // [K]
    int* out = (int*)d_out;

    const int DL1 = DSPL;                 // 25344
    const int DL2 = D - DSPL;             // 24913
    const int nch1 = (DL1 + 31) / 32;     // 792
    const int nch2 = (DL2 + 31) / 32;     // 779
    const int nchmax = nch1;

    size_t cur = 0;
    auto alloc = [&](size_t bytes) -> void* {
        cur = (cur + 255) & ~(size_t)255;
        void* p = (char*)d_ws + cur;
        cur += bytes;
        return p;
    };

    unsigned short* lq      = (unsigned short*)alloc((size_t)nchmax * B * 32 * 2); // 13.0MB
    float*          crossA  = (float*)alloc((size_t)B * K * 4);                    //  2.1MB
    float*          selfp   = (float*)alloc((size_t)12 * K * 4);
    float*          selftot = (float*)alloc((size_t)K * 4);
    int*            cand    = (int*)alloc((size_t)B * NC * 4);
    int*            need    = (int*)alloc((size_t)B * 4);
    double*         pp      = (double*)alloc((size_t)B * 2 * NC * 8);
    const size_t fixed_end  = cur;

    // partials ladder: pch in {4,2,1}
    int pch = 1;
    for (int s = 4; s >= 1; s >>= 1) {
        if (fixed_end + (size_t)s * B * K * 4 + 256 <= ws_size) { pch = s; break; }
    }
    float* part = (float*)alloc((size_t)pch * B * K * 4);                          //  8.4MB @4

    const int dc1 = ((DL1 + pch - 1) / pch + 31) & ~31;   // 6336 @pch=4
    const int dc2 = ((DL2 + pch - 1) / pch + 31) & ~31;   // 6240 @pch=4

    // ---- phase 0: cols [0, DL1) ----
    lq_kernel<<<2048, 256, 0, stream>>>(query, lq, 0, DL1, nch1);
    gemm_kernel<<<64 * pch, 512, 0, stream>>>(anchor, lq, part, selfp,
                                              dc1, DL1, nch1 * 32, 0, 0);
    reduce_kernel<<<B * K / 4 / 256, 256, 0, stream>>>(part, crossA, pch);

    // ---- phase 1: cols [DL1, D) ----
    lq_kernel<<<2048, 256, 0, stream>>>(query, lq, DSPL, DL2, nch2);
    gemm_kernel<<<64 * pch, 512, 0, stream>>>(anchor, lq, part, selfp,
                                              dc2, DL2, nch2 * 32, DSPL, pch);

    selfsum_kernel<<<K / 256, 256, 0, stream>>>(selfp, selftot, 2 * pch);
    topk_kernel<<<B, 256, 0, stream>>>(crossA, part, selftot, cand, need, pch);
    rescore_kernel<<<dim3(B, 2), 512, 0, stream>>>(query, anchor, cand, need, pp);
    final_kernel<<<1, 256, 0, stream>>>(pp, selftot, cand, need, label, out);
}